// Round 6
// baseline (360.251 us; speedup 1.0000x reference)
//
#include <hip/hip_runtime.h>
#include <hip/hip_bf16.h>
#include <stdint.h>

#define BB 4
#define NN 512
#define HH 8

typedef __attribute__((ext_vector_type(4))) float f32x4;
typedef __attribute__((ext_vector_type(8))) __bf16 bf16x8;
typedef unsigned short u16;

union BV8 { bf16x8 v; u16 u[8]; };

__device__ __forceinline__ u16 f2bf(float f) {
    uint32_t u = __float_as_uint(f);
    u += 0x7FFFu + ((u >> 16) & 1u);   // round-to-nearest-even
    return (u16)(u >> 16);
}

#define GLD16(gp, lp) __builtin_amdgcn_global_load_lds( \
    (const __attribute__((address_space(1))) void*)(gp), \
    (__attribute__((address_space(3))) void*)(lp), 16, 0, 0)

// ---------------- diagnostic: fills fp32 output with a marker ----------------
__global__ __launch_bounds__(256) void marker_k(float* __restrict__ out,
                                                float val, int n) {
    int i = blockIdx.x * 256 + threadIdx.x;
    if (i < n) out[i] = val;
}

// ---------------- P0: We^T -> bf16, and sg[b,d] = g@Wg + bg + be + b2 ----------------
__global__ __launch_bounds__(256) void prep0(
    const float* __restrict__ We, const float* __restrict__ graph,
    const float* __restrict__ Wg, const float* __restrict__ bg,
    const float* __restrict__ be, const float* __restrict__ b2,
    u16* __restrict__ weT, float* __restrict__ sg) {
    int blk = blockIdx.x, tid = threadIdx.x;
    if (blk == 0) {
        for (int idx = tid; idx < 128 * 128; idx += 256) {
            int n = idx >> 7, k = idx & 127;
            weT[idx] = f2bf(We[k * 128 + n]);   // weT[n][k] = We[k][n]
        }
    } else {
        int b = blk - 1;
        if (tid < 128) {
            float acc = bg[tid] + be[tid] + b2[tid];
            for (int k = 0; k < 128; ++k)
                acc += graph[b * 128 + k] * Wg[k * 128 + tid];
            sg[b * 128 + tid] = acc;
        }
    }
}

// ---------------- P1: s1T = (zW1+b1)^T, s2c = zW2+sg, values, skip ----------------
__global__ __launch_bounds__(256) void prep1(
    const float* __restrict__ node, const float* __restrict__ hidden,
    const float* __restrict__ Wm, const float* __restrict__ bm,
    const float* __restrict__ Ws, const float* __restrict__ bs,
    const float* __restrict__ W1, const float* __restrict__ b1,
    const float* __restrict__ W2, const float* __restrict__ sg,
    float* __restrict__ s1T, float* __restrict__ s2c,
    float* __restrict__ sv, float* __restrict__ ss) {
    __shared__ float zsh[8 * 256];
    int blk = blockIdx.x;            // 256 blocks: 64 per batch, 8 rows each
    int b = blk >> 6;
    int n0 = (blk & 63) << 3;
    int tid = threadIdx.x;
    for (int idx = tid; idx < 8 * 256; idx += 256) {
        int row = idx >> 8, k = idx & 255;
        size_t g = (size_t)(b * NN + n0 + row) * 128;
        zsh[idx] = (k < 128) ? node[g + k] : hidden[g + k - 128];
    }
    __syncthreads();
    int half = tid >> 7;             // 0/1 -> rows 0-3 / 4-7
    int t = tid & 127;               // output dim
    int r0 = half * 4;
    float am[4] = {0,0,0,0}, a1[4] = {0,0,0,0}, a2[4] = {0,0,0,0}, as_[4] = {0,0,0,0};
    for (int k = 0; k < 256; ++k) {
        float wm = Wm[k * 128 + t], w1 = W1[k * 128 + t];
        float w2 = W2[k * 128 + t], ws = Ws[k * 128 + t];
        #pragma unroll
        for (int r = 0; r < 4; ++r) {
            float z = zsh[(r0 + r) * 256 + k];
            am[r] += z * wm; a1[r] += z * w1; a2[r] += z * w2; as_[r] += z * ws;
        }
    }
    float sgv = sg[b * 128 + t];
    #pragma unroll
    for (int r = 0; r < 4; ++r) {
        int n = n0 + r0 + r;         // node index j
        size_t rowoff = (size_t)(b * NN + n) * 128 + t;
        s1T[(size_t)(b * 128 + t) * NN + n] = a1[r] + b1[t];   // transposed
        s2c[rowoff] = a2[r] + sgv;
        ss[rowoff]  = as_[r] + bs[t];
        // values in (b,h,n,16) layout for coalesced PV reads
        sv[(size_t)((b * HH + (t >> 4)) * NN + n) * 16 + (t & 15)] = am[r] + bm[t];
    }
}

// ---------------- Fused v3: pipelined gload_lds edge GEMM + logits + softmax + PV ----------------
// block = (b, i); 4 waves. Wave wid owns n-cols [wid*32, +32) (heads 2wid, 2wid+1).
// j in 16 strips of 32 rows, TRIPLE-buffered staging, raw-barrier counted pipeline.
__global__ __launch_bounds__(256, 2) void fused_att3(
    const float* __restrict__ edge, const u16* __restrict__ weT,
    const float* __restrict__ s1T, const float* __restrict__ s2c,
    const float* __restrict__ adj, const float* __restrict__ Aw,
    const float* __restrict__ Ab, const float* __restrict__ sv,
    const float* __restrict__ ss, float* __restrict__ out) {
    __shared__ __align__(16) float stage[3][32 * 128];   // 3 x 16 KB edge strips
    __shared__ float logit_lds[HH][NN];                  // 16 KB
    __shared__ float mask_lds[NN];                       // 2 KB

    // XCD-chunked swizzle: HW round-robins blockIdx across 8 XCDs; remap so each
    // XCD gets a contiguous logical range -> same-b blocks share an XCD's L2.
    const int bid = (blockIdx.x & 7) * 256 + (blockIdx.x >> 3);
    const int i = bid & (NN - 1);
    const int b = bid >> 9;
    const int tid = threadIdx.x;
    const int lane = tid & 63, wid = tid >> 6;
    const int l15 = lane & 15, l4 = lane >> 4;

    const float* ebase = edge + (size_t)(b * NN + i) * NN * 128;
    const float* s1b = s1T + (size_t)b * 128 * NN;

    // strip s: rows [s*32,+32). slot = r*32+gs (16B granules); dest linear,
    // source granule g = gs ^ (r&3): XOR stays WITHIN a 64B sector (merge-safe).
    #define STAGE(buf, s) do {                                              \
        const float* sb = ebase + (size_t)(s) * 32 * 128;                   \
        _Pragma("unroll")                                                   \
        for (int it = 0; it < 4; ++it) {                                    \
            const int slotu = it * 256 + wid * 64;                          \
            float* ldst = &stage[buf][slotu * 4];                           \
            const int myslot = slotu + lane;                                \
            const int r = myslot >> 5, gs = myslot & 31;                    \
            const int g = gs ^ (r & 3);                                     \
            GLD16(sb + r * 128 + g * 4, ldst);                              \
        }                                                                   \
    } while (0)

    STAGE(0, 0);
    STAGE(1, 1);

    // B-fragments (We^T slice for this wave's 32 cols) -> VGPRs (L2-shared)
    bf16x8 bfr[2][4];
    #pragma unroll
    for (int nf = 0; nf < 2; ++nf) {
        const int bn = wid * 32 + nf * 16 + l15;
        #pragma unroll
        for (int kk = 0; kk < 4; ++kk)
            bfr[nf][kk] = *(const bf16x8*)(weT + bn * 128 + kk * 32 + l4 * 8);
    }

    const float* arow = adj + (size_t)(b * NN + i) * NN;
    for (int j = tid; j < NN; j += 256) mask_lds[j] = (arow[j] - 1.0f) * 1e9f;

    float s2v[2], awv[2], abv[2];
    #pragma unroll
    for (int nf = 0; nf < 2; ++nf) {
        const int n = wid * 32 + nf * 16 + l15;
        s2v[nf] = s2c[(size_t)(b * NN + i) * 128 + n];
        awv[nf] = Aw[n];
        abv[nf] = Ab[(wid * 2) + nf];
    }
    __syncthreads();   // full barrier: mask visible, strips 0-1 drained

    for (int s = 0; s < 16; ++s) {
        const int strip0 = s * 32;
        const float* st = stage[s % 3];

        // s1 loads FIRST (older than this iter's STAGE -> their wait leaves it in flight)
        float4 s1v[2][2];
        #pragma unroll
        for (int mf = 0; mf < 2; ++mf)
            #pragma unroll
            for (int nf = 0; nf < 2; ++nf)
                s1v[mf][nf] = *(const float4*)(
                    s1b + (size_t)(wid * 32 + nf * 16 + l15) * NN
                        + strip0 + mf * 16 + l4 * 4);
        __builtin_amdgcn_sched_barrier(0);
        if (s + 2 < 16) STAGE((s + 2) % 3, s + 2);

        // A fragments from LDS (swizzled), fp32 -> bf16
        bf16x8 af[2][4];
        #pragma unroll
        for (int mf = 0; mf < 2; ++mf) {
            const int R = mf * 16 + l15;
            #pragma unroll
            for (int kk = 0; kk < 4; ++kk) {
                const int g0 = kk * 8 + l4 * 2;
                const float4 lo = *(const float4*)&st[(R * 32 + (g0 ^ (R & 3))) * 4];
                const float4 hi = *(const float4*)&st[(R * 32 + ((g0 + 1) ^ (R & 3))) * 4];
                BV8 t;
                t.u[0] = f2bf(lo.x); t.u[1] = f2bf(lo.y);
                t.u[2] = f2bf(lo.z); t.u[3] = f2bf(lo.w);
                t.u[4] = f2bf(hi.x); t.u[5] = f2bf(hi.y);
                t.u[6] = f2bf(hi.z); t.u[7] = f2bf(hi.w);
                af[mf][kk] = t.v;
            }
        }

        f32x4 acc[2][2];
        #pragma unroll
        for (int mf = 0; mf < 2; ++mf)
            #pragma unroll
            for (int nf = 0; nf < 2; ++nf)
                acc[mf][nf] = (f32x4){s2v[nf], s2v[nf], s2v[nf], s2v[nf]};

        #pragma unroll
        for (int kk = 0; kk < 4; ++kk)
            #pragma unroll
            for (int mf = 0; mf < 2; ++mf) {
                acc[mf][0] = __builtin_amdgcn_mfma_f32_16x16x32_bf16(af[mf][kk], bfr[0][kk], acc[mf][0], 0, 0, 0);
                acc[mf][1] = __builtin_amdgcn_mfma_f32_16x16x32_bf16(af[mf][kk], bfr[1][kk], acc[mf][1], 0, 0, 0);
            }

        // epilogue: + s1, leaky, *Aw, 16-lane reduce -> logit_lds
        #pragma unroll
        for (int mf = 0; mf < 2; ++mf) {
            #pragma unroll
            for (int nf = 0; nf < 2; ++nf) {
                const float s1r[4] = {s1v[mf][nf].x, s1v[mf][nf].y,
                                      s1v[mf][nf].z, s1v[mf][nf].w};
                #pragma unroll
                for (int r = 0; r < 4; ++r) {
                    float p = acc[mf][nf][r] + s1r[r];
                    p = (p > 0.0f) ? p : 0.01f * p;
                    float tl = p * awv[nf];
                    tl += __shfl_xor(tl, 1);
                    tl += __shfl_xor(tl, 2);
                    tl += __shfl_xor(tl, 4);
                    tl += __shfl_xor(tl, 8);
                    if (l15 == 0)
                        logit_lds[wid * 2 + nf][strip0 + mf * 16 + l4 * 4 + r] = tl + abv[nf];
                }
            }
        }
        __builtin_amdgcn_s_barrier();          // raw: no vmcnt(0) drain
        __builtin_amdgcn_sched_barrier(0);     // pin: no hoisting across barrier
    }
    __syncthreads();   // full: logit_lds visible to softmax readers

    // masked softmax: wave wid handles heads wid*2, wid*2+1 (rows it wrote itself)
    #pragma unroll
    for (int hh = 0; hh < 2; ++hh) {
        const int h = wid * 2 + hh;
        float lv[8];
        float m = -3.0e38f;
        #pragma unroll
        for (int q = 0; q < 8; ++q) {
            float l = logit_lds[h][lane + q * 64] + mask_lds[lane + q * 64];
            lv[q] = l;
            m = fmaxf(m, l);
        }
        #pragma unroll
        for (int off = 32; off; off >>= 1) m = fmaxf(m, __shfl_xor(m, off));
        float s = 0.0f;
        #pragma unroll
        for (int q = 0; q < 8; ++q) { lv[q] = __expf(lv[q] - m); s += lv[q]; }
        #pragma unroll
        for (int off = 32; off; off >>= 1) s += __shfl_xor(s, off);
        const float inv = 1.0f / s;
        #pragma unroll
        for (int q = 0; q < 8; ++q)
            logit_lds[h][lane + q * 64] = lv[q] * inv;
    }
    __syncthreads();

    // PV: wave wid -> heads 2wid,2wid+1. Lane owns j = lane (mod 64); 16 d-accs in regs.
    // sv reads: 64 B/lane, lanes consecutive -> fully coalesced.
    float* scr = &stage[0][0] + wid * 1280;    // 64 lanes x 20 floats (padded, bank-spread)
    const float* ssb = ss + (size_t)(b * NN + i) * 128;
    float outv[2];
    #pragma unroll
    for (int hh = 0; hh < 2; ++hh) {
        const int h = wid * 2 + hh;
        const float* svh = sv + (size_t)(b * HH + h) * NN * 16;
        f32x4 a0 = {0,0,0,0}, a1 = {0,0,0,0}, a2 = {0,0,0,0}, a3 = {0,0,0,0};
        #pragma unroll
        for (int q = 0; q < 8; ++q) {
            const int j = q * 64 + lane;
            const float c = logit_lds[h][j];
            const float4* vj = (const float4*)(svh + (size_t)j * 16);
            const float4 v0 = vj[0], v1 = vj[1], v2 = vj[2], v3 = vj[3];
            a0[0] += c * v0.x; a0[1] += c * v0.y; a0[2] += c * v0.z; a0[3] += c * v0.w;
            a1[0] += c * v1.x; a1[1] += c * v1.y; a1[2] += c * v1.z; a1[3] += c * v1.w;
            a2[0] += c * v2.x; a2[1] += c * v2.y; a2[2] += c * v2.z; a2[3] += c * v2.w;
            a3[0] += c * v3.x; a3[1] += c * v3.y; a3[2] += c * v3.z; a3[3] += c * v3.w;
        }
        // per-wave scratch reduce (same-wave LDS, no barrier needed)
        *(f32x4*)(scr + lane * 20 + 0)  = a0;
        *(f32x4*)(scr + lane * 20 + 4)  = a1;
        *(f32x4*)(scr + lane * 20 + 8)  = a2;
        *(f32x4*)(scr + lane * 20 + 12) = a3;
        float p = 0.0f;
        #pragma unroll
        for (int t = 0; t < 16; ++t)
            p += scr[(l4 * 16 + t) * 20 + l15];
        p += __shfl_xor(p, 16);
        p += __shfl_xor(p, 32);
        outv[hh] = p;     // lanes 0-15 hold sum for d = l15
    }
    if (lane < 16) {
        const size_t o = (size_t)(b * NN + i) * 128 + (wid * 2) * 16 + lane;
        out[o]      = fmaxf(outv[0] + ssb[(wid * 2) * 16 + lane], 0.0f);
        out[o + 16] = fmaxf(outv[1] + ssb[(wid * 2) * 16 + lane + 16], 0.0f);
    }
    #undef STAGE
}

extern "C" void kernel_launch(void* const* d_in, const int* in_sizes, int n_in,
                              void* d_out, int out_size, void* d_ws, size_t ws_size,
                              hipStream_t stream) {
    const float* node   = (const float*)d_in[0];
    const float* edge   = (const float*)d_in[1];
    const float* graph  = (const float*)d_in[2];
    const float* adj    = (const float*)d_in[3];
    const float* hidden = (const float*)d_in[4];
    const float* Wm = (const float*)d_in[5];
    const float* bm = (const float*)d_in[6];
    const float* Ws = (const float*)d_in[7];
    const float* bs = (const float*)d_in[8];
    const float* W1 = (const float*)d_in[9];
    const float* b1 = (const float*)d_in[10];
    const float* W2 = (const float*)d_in[11];
    const float* b2 = (const float*)d_in[12];
    const float* We = (const float*)d_in[13];
    const float* be = (const float*)d_in[14];
    const float* Wg = (const float*)d_in[15];
    const float* bg = (const float*)d_in[16];
    const float* Aw = (const float*)d_in[17];
    const float* Ab = (const float*)d_in[18];

    float* outp = (float*)d_out;   // reference output dtype is float32
    const size_t WS_NEEDED = 34816 + 4u * 1048576u;   // ~4.03 MiB

    if (ws_size < WS_NEEDED) {
        marker_k<<<(out_size + 255) / 256, 256, 0, stream>>>(
            outp, 2000.0f + (float)(ws_size >> 20), out_size);
        return;
    }

    char* ws = (char*)d_ws;
    u16*   weT = (u16*)ws;                                // 32768 B
    float* sg  = (float*)(ws + 32768);                    // 2048 B
    float* s1T = (float*)(ws + 34816);                    // 1 MiB (transposed [b][n][j])
    float* s2c = (float*)(ws + 34816 + 1048576);          // 1 MiB
    float* sv  = (float*)(ws + 34816 + 2 * 1048576);      // 1 MiB
    float* ss  = (float*)(ws + 34816 + 3 * 1048576);      // 1 MiB

    prep0<<<1 + BB, 256, 0, stream>>>(We, graph, Wg, bg, be, b2, weT, sg);
    prep1<<<256, 256, 0, stream>>>(node, hidden, Wm, bm, Ws, bs, W1, b1, W2,
                                   sg, s1T, s2c, sv, ss);
    fused_att3<<<BB * NN, 256, 0, stream>>>(edge, weT, s1T, s2c, adj, Aw, Ab,
                                            sv, ss, outp);
}

// Round 7
// 241.722 us; speedup vs baseline: 1.4904x; 1.4904x over previous
//
#include <hip/hip_runtime.h>
#include <hip/hip_bf16.h>
#include <stdint.h>

#define BB 4
#define NN 512
#define HH 8

typedef __attribute__((ext_vector_type(4))) float f32x4;
typedef __attribute__((ext_vector_type(8))) __bf16 bf16x8;
typedef unsigned short u16;

union BV8 { bf16x8 v; u16 u[8]; };

__device__ __forceinline__ u16 f2bf(float f) {
    uint32_t u = __float_as_uint(f);
    u += 0x7FFFu + ((u >> 16) & 1u);   // round-to-nearest-even
    return (u16)(u >> 16);
}

#define GLD16(gp, lp) __builtin_amdgcn_global_load_lds( \
    (const __attribute__((address_space(1))) void*)(gp), \
    (__attribute__((address_space(3))) void*)(lp), 16, 0, 0)

// ---------------- diagnostic: fills fp32 output with a marker ----------------
__global__ __launch_bounds__(256) void marker_k(float* __restrict__ out,
                                                float val, int n) {
    int i = blockIdx.x * 256 + threadIdx.x;
    if (i < n) out[i] = val;
}

// ---------------- P0: We^T -> bf16, and sg[b,d] = g@Wg + bg + be + b2 ----------------
__global__ __launch_bounds__(256) void prep0(
    const float* __restrict__ We, const float* __restrict__ graph,
    const float* __restrict__ Wg, const float* __restrict__ bg,
    const float* __restrict__ be, const float* __restrict__ b2,
    u16* __restrict__ weT, float* __restrict__ sg) {
    int blk = blockIdx.x, tid = threadIdx.x;
    if (blk == 0) {
        for (int idx = tid; idx < 128 * 128; idx += 256) {
            int n = idx >> 7, k = idx & 127;
            weT[idx] = f2bf(We[k * 128 + n]);   // weT[n][k] = We[k][n]
        }
    } else {
        int b = blk - 1;
        if (tid < 128) {
            float acc = bg[tid] + be[tid] + b2[tid];
            for (int k = 0; k < 128; ++k)
                acc += graph[b * 128 + k] * Wg[k * 128 + tid];
            sg[b * 128 + tid] = acc;
        }
    }
}

// ---------------- P1: s1 = zW1+b1, s2c = zW2+sg, values, skip ----------------
__global__ __launch_bounds__(256) void prep1(
    const float* __restrict__ node, const float* __restrict__ hidden,
    const float* __restrict__ Wm, const float* __restrict__ bm,
    const float* __restrict__ Ws, const float* __restrict__ bs,
    const float* __restrict__ W1, const float* __restrict__ b1,
    const float* __restrict__ W2, const float* __restrict__ sg,
    float* __restrict__ s1, float* __restrict__ s2c,
    float* __restrict__ sv, float* __restrict__ ss) {
    __shared__ float zsh[8 * 256];
    int blk = blockIdx.x;            // 256 blocks: 64 per batch, 8 rows each
    int b = blk >> 6;
    int n0 = (blk & 63) << 3;
    int tid = threadIdx.x;
    for (int idx = tid; idx < 8 * 256; idx += 256) {
        int row = idx >> 8, k = idx & 255;
        size_t g = (size_t)(b * NN + n0 + row) * 128;
        zsh[idx] = (k < 128) ? node[g + k] : hidden[g + k - 128];
    }
    __syncthreads();
    int half = tid >> 7;             // 0/1 -> rows 0-3 / 4-7
    int t = tid & 127;               // output dim
    int r0 = half * 4;
    float am[4] = {0,0,0,0}, a1[4] = {0,0,0,0}, a2[4] = {0,0,0,0}, as_[4] = {0,0,0,0};
    for (int k = 0; k < 256; ++k) {
        float wm = Wm[k * 128 + t], w1 = W1[k * 128 + t];
        float w2 = W2[k * 128 + t], ws = Ws[k * 128 + t];
        #pragma unroll
        for (int r = 0; r < 4; ++r) {
            float z = zsh[(r0 + r) * 256 + k];
            am[r] += z * wm; a1[r] += z * w1; a2[r] += z * w2; as_[r] += z * ws;
        }
    }
    float sgv = sg[b * 128 + t];
    #pragma unroll
    for (int r = 0; r < 4; ++r) {
        int n = n0 + r0 + r;         // node index j
        size_t rowoff = (size_t)(b * NN + n) * 128 + t;
        s1[rowoff]  = a1[r] + b1[t];
        s2c[rowoff] = a2[r] + sgv;
        ss[rowoff]  = as_[r] + bs[t];
        // values in (b,h,n,16) layout for coalesced PV reads
        sv[(size_t)((b * HH + (t >> 4)) * NN + n) * 16 + (t & 15)] = am[r] + bm[t];
    }
}

// ---------------- Fused v4: operand-swapped MFMA (register-axis head reduce) ----------------
// block = (b, i); 4 waves. Wave wid owns n-cols [wid*32,+32) = heads 2wid,2wid+1.
// D[n][j] = mfma(A=weT, B=edge): lane holds n = base+l4*4+r (regs), j = l15.
// Head-dot reduces over REGISTERS + 2 shfl (xor16,32) instead of 4-shfl chains.
__global__ __launch_bounds__(256, 3) void fused_att4(
    const float* __restrict__ edge, const u16* __restrict__ weT,
    const float* __restrict__ s1, const float* __restrict__ s2c,
    const float* __restrict__ adj, const float* __restrict__ Aw,
    const float* __restrict__ Ab, const float* __restrict__ sv,
    const float* __restrict__ ss, float* __restrict__ out) {
    __shared__ __align__(16) float stage[2][32 * 128];   // 2 x 16 KB edge strips
    __shared__ float logit_lds[HH][NN];                  // 16 KB
    __shared__ float mask_lds[NN];                       // 2 KB

    // XCD-chunked swizzle: same-b blocks share an XCD's L2 (s1/sv/s2c resident)
    const int bid = (blockIdx.x & 7) * 256 + (blockIdx.x >> 3);
    const int i = bid & (NN - 1);
    const int b = bid >> 9;
    const int tid = threadIdx.x;
    const int lane = tid & 63, wid = tid >> 6;
    const int l15 = lane & 15, l4 = lane >> 4;

    const float* ebase = edge + (size_t)(b * NN + i) * NN * 128;
    const float* s1b = s1 + (size_t)b * NN * 128;

    // strip s: rows [s*32,+32). dest linear 16B granules; source granule
    // g = gs ^ (r&3) stays WITHIN a 64B sector (coalescer merge-safe).
    #define STAGE(buf, s) do {                                              \
        const float* sb = ebase + (size_t)(s) * 32 * 128;                   \
        _Pragma("unroll")                                                   \
        for (int it = 0; it < 4; ++it) {                                    \
            const int slotu = it * 256 + wid * 64;                          \
            float* ldst = &stage[buf][slotu * 4];                           \
            const int myslot = slotu + lane;                                \
            const int r = myslot >> 5, gs = myslot & 31;                    \
            const int g = gs ^ (r & 3);                                     \
            GLD16(sb + r * 128 + g * 4, ldst);                              \
        }                                                                   \
    } while (0)

    STAGE(0, 0);

    // A-fragments: weT rows n = wid*32+nf*16+l15, k = kk*32+l4*8.. (L2-shared)
    bf16x8 afw[2][4];
    #pragma unroll
    for (int nf = 0; nf < 2; ++nf) {
        const int bn = wid * 32 + nf * 16 + l15;
        #pragma unroll
        for (int kk = 0; kk < 4; ++kk)
            afw[nf][kk] = *(const bf16x8*)(weT + bn * 128 + kk * 32 + l4 * 8);
    }

    const float* arow = adj + (size_t)(b * NN + i) * NN;
    for (int j = tid; j < NN; j += 256) mask_lds[j] = (arow[j] - 1.0f) * 1e9f;

    // per-lane float4 constants over n = wid*32+nf*16+l4*4 .. +3
    float4 s2v4[2], aw4[2];
    float abv[2];
    #pragma unroll
    for (int nf = 0; nf < 2; ++nf) {
        const int n0 = wid * 32 + nf * 16 + l4 * 4;
        s2v4[nf] = *(const float4*)(s2c + (size_t)(b * NN + i) * 128 + n0);
        aw4[nf]  = *(const float4*)(Aw + n0);
        abv[nf]  = Ab[wid * 2 + nf];
    }
    __syncthreads();   // strip 0 staged (vmcnt drained), mask visible

    for (int s = 0; s < 16; ++s) {
        const int strip0 = s * 32;
        const float* st = stage[s & 1];

        // s1 loads FIRST (epilogue wait then leaves the newer STAGE in flight)
        float4 s1v[2][2];
        #pragma unroll
        for (int jf = 0; jf < 2; ++jf)
            #pragma unroll
            for (int nf = 0; nf < 2; ++nf)
                s1v[jf][nf] = *(const float4*)(
                    s1b + (size_t)(strip0 + jf * 16 + l15) * 128
                        + wid * 32 + nf * 16 + l4 * 4);
        __builtin_amdgcn_sched_barrier(0);
        if (s < 15) STAGE((s + 1) & 1, s + 1);   // async DMA across this iter's compute

        // B-fragments (edge) from LDS: col j = jf*16+l15, k = kk*32+l4*8..
        bf16x8 bfe[2][4];
        #pragma unroll
        for (int jf = 0; jf < 2; ++jf) {
            const int R = jf * 16 + l15;
            #pragma unroll
            for (int kk = 0; kk < 4; ++kk) {
                const int g0 = kk * 8 + l4 * 2;
                const float4 lo = *(const float4*)&st[(R * 32 + (g0 ^ (R & 3))) * 4];
                const float4 hi = *(const float4*)&st[(R * 32 + ((g0 + 1) ^ (R & 3))) * 4];
                BV8 t;
                t.u[0] = f2bf(lo.x); t.u[1] = f2bf(lo.y);
                t.u[2] = f2bf(lo.z); t.u[3] = f2bf(lo.w);
                t.u[4] = f2bf(hi.x); t.u[5] = f2bf(hi.y);
                t.u[6] = f2bf(hi.z); t.u[7] = f2bf(hi.w);
                bfe[jf][kk] = t.v;
            }
        }

        // acc[nf][jf]: D rows = n (l4*4+r), cols = j (l15); init with s2c(n)
        f32x4 acc[2][2];
        #pragma unroll
        for (int nf = 0; nf < 2; ++nf) {
            const f32x4 ini = {s2v4[nf].x, s2v4[nf].y, s2v4[nf].z, s2v4[nf].w};
            acc[nf][0] = ini;
            acc[nf][1] = ini;
        }

        #pragma unroll
        for (int kk = 0; kk < 4; ++kk)
            #pragma unroll
            for (int jf = 0; jf < 2; ++jf) {
                acc[0][jf] = __builtin_amdgcn_mfma_f32_16x16x32_bf16(afw[0][kk], bfe[jf][kk], acc[0][jf], 0, 0, 0);
                acc[1][jf] = __builtin_amdgcn_mfma_f32_16x16x32_bf16(afw[1][kk], bfe[jf][kk], acc[1][jf], 0, 0, 0);
            }

        // epilogue: +s1, leaky, dot(Aw) over registers, 2-shfl reduce over l4
        #pragma unroll
        for (int jf = 0; jf < 2; ++jf) {
            #pragma unroll
            for (int nf = 0; nf < 2; ++nf) {
                const float s1r[4] = {s1v[jf][nf].x, s1v[jf][nf].y,
                                      s1v[jf][nf].z, s1v[jf][nf].w};
                const float awr[4] = {aw4[nf].x, aw4[nf].y, aw4[nf].z, aw4[nf].w};
                float t = 0.0f;
                #pragma unroll
                for (int r = 0; r < 4; ++r) {
                    float p = acc[nf][jf][r] + s1r[r];
                    p = (p > 0.0f) ? p : 0.01f * p;
                    t += p * awr[r];
                }
                t += __shfl_xor(t, 16);
                t += __shfl_xor(t, 32);
                if (lane < 16)
                    logit_lds[wid * 2 + nf][strip0 + jf * 16 + l15] = t + abv[nf];
            }
        }
        __syncthreads();   // drains vmcnt: next strip staged; buffers safe
    }

    // masked softmax: wave wid handles heads 2wid, 2wid+1 (rows it wrote itself)
    #pragma unroll
    for (int hh = 0; hh < 2; ++hh) {
        const int h = wid * 2 + hh;
        float lv[8];
        float m = -3.0e38f;
        #pragma unroll
        for (int q = 0; q < 8; ++q) {
            float l = logit_lds[h][lane + q * 64] + mask_lds[lane + q * 64];
            lv[q] = l;
            m = fmaxf(m, l);
        }
        #pragma unroll
        for (int off = 32; off; off >>= 1) m = fmaxf(m, __shfl_xor(m, off));
        float s = 0.0f;
        #pragma unroll
        for (int q = 0; q < 8; ++q) { lv[q] = __expf(lv[q] - m); s += lv[q]; }
        #pragma unroll
        for (int off = 32; off; off >>= 1) s += __shfl_xor(s, off);
        const float inv = 1.0f / s;
        #pragma unroll
        for (int q = 0; q < 8; ++q)
            logit_lds[h][lane + q * 64] = lv[q] * inv;
    }
    __syncthreads();

    // PV: wave wid -> heads 2wid,2wid+1. Lane owns j = lane (mod 64).
    float* scr = &stage[0][0] + wid * 1280;    // per-wave scratch (disjoint)
    const float* ssb = ss + (size_t)(b * NN + i) * 128;
    float outv[2];
    #pragma unroll
    for (int hh = 0; hh < 2; ++hh) {
        const int h = wid * 2 + hh;
        const float* svh = sv + (size_t)(b * HH + h) * NN * 16;
        f32x4 a0 = {0,0,0,0}, a1 = {0,0,0,0}, a2 = {0,0,0,0}, a3 = {0,0,0,0};
        #pragma unroll
        for (int q = 0; q < 8; ++q) {
            const int j = q * 64 + lane;
            const float c = logit_lds[h][j];
            const float4* vj = (const float4*)(svh + (size_t)j * 16);
            const float4 v0 = vj[0], v1 = vj[1], v2 = vj[2], v3 = vj[3];
            a0[0] += c * v0.x; a0[1] += c * v0.y; a0[2] += c * v0.z; a0[3] += c * v0.w;
            a1[0] += c * v1.x; a1[1] += c * v1.y; a1[2] += c * v1.z; a1[3] += c * v1.w;
            a2[0] += c * v2.x; a2[1] += c * v2.y; a2[2] += c * v2.z; a2[3] += c * v2.w;
            a3[0] += c * v3.x; a3[1] += c * v3.y; a3[2] += c * v3.z; a3[3] += c * v3.w;
        }
        *(f32x4*)(scr + lane * 20 + 0)  = a0;
        *(f32x4*)(scr + lane * 20 + 4)  = a1;
        *(f32x4*)(scr + lane * 20 + 8)  = a2;
        *(f32x4*)(scr + lane * 20 + 12) = a3;
        float p = 0.0f;
        #pragma unroll
        for (int t = 0; t < 16; ++t)
            p += scr[(l4 * 16 + t) * 20 + l15];
        p += __shfl_xor(p, 16);
        p += __shfl_xor(p, 32);
        outv[hh] = p;     // lanes 0-15 hold sum for d = l15
    }
    if (lane < 16) {
        const size_t o = (size_t)(b * NN + i) * 128 + (wid * 2) * 16 + lane;
        out[o]      = fmaxf(outv[0] + ssb[(wid * 2) * 16 + lane], 0.0f);
        out[o + 16] = fmaxf(outv[1] + ssb[(wid * 2) * 16 + lane + 16], 0.0f);
    }
    #undef STAGE
}

extern "C" void kernel_launch(void* const* d_in, const int* in_sizes, int n_in,
                              void* d_out, int out_size, void* d_ws, size_t ws_size,
                              hipStream_t stream) {
    const float* node   = (const float*)d_in[0];
    const float* edge   = (const float*)d_in[1];
    const float* graph  = (const float*)d_in[2];
    const float* adj    = (const float*)d_in[3];
    const float* hidden = (const float*)d_in[4];
    const float* Wm = (const float*)d_in[5];
    const float* bm = (const float*)d_in[6];
    const float* Ws = (const float*)d_in[7];
    const float* bs = (const float*)d_in[8];
    const float* W1 = (const float*)d_in[9];
    const float* b1 = (const float*)d_in[10];
    const float* W2 = (const float*)d_in[11];
    const float* b2 = (const float*)d_in[12];
    const float* We = (const float*)d_in[13];
    const float* be = (const float*)d_in[14];
    const float* Wg = (const float*)d_in[15];
    const float* bg = (const float*)d_in[16];
    const float* Aw = (const float*)d_in[17];
    const float* Ab = (const float*)d_in[18];

    float* outp = (float*)d_out;   // reference output dtype is float32
    const size_t WS_NEEDED = 34816 + 4u * 1048576u;   // ~4.03 MiB

    if (ws_size < WS_NEEDED) {
        marker_k<<<(out_size + 255) / 256, 256, 0, stream>>>(
            outp, 2000.0f + (float)(ws_size >> 20), out_size);
        return;
    }

    char* ws = (char*)d_ws;
    u16*   weT = (u16*)ws;                                // 32768 B
    float* sg  = (float*)(ws + 32768);                    // 2048 B
    float* s1  = (float*)(ws + 34816);                    // 1 MiB
    float* s2c = (float*)(ws + 34816 + 1048576);          // 1 MiB
    float* sv  = (float*)(ws + 34816 + 2 * 1048576);      // 1 MiB
    float* ss  = (float*)(ws + 34816 + 3 * 1048576);      // 1 MiB

    prep0<<<1 + BB, 256, 0, stream>>>(We, graph, Wg, bg, be, b2, weT, sg);
    prep1<<<256, 256, 0, stream>>>(node, hidden, Wm, bm, Ws, bs, W1, b1, W2,
                                   sg, s1, s2c, sv, ss);
    fused_att4<<<BB * NN, 256, 0, stream>>>(edge, weT, s1, s2c, adj, Aw, Ab,
                                            sv, ss, outp);
}

// Round 9
// 215.909 us; speedup vs baseline: 1.6685x; 1.1196x over previous
//
#include <hip/hip_runtime.h>
#include <hip/hip_bf16.h>
#include <stdint.h>

#define BB 4
#define NN 512
#define HH 8

typedef __attribute__((ext_vector_type(4))) float f32x4;
typedef __attribute__((ext_vector_type(8))) __bf16 bf16x8;
typedef unsigned short u16;

__device__ __forceinline__ u16 f2bf(float f) {
    uint32_t u = __float_as_uint(f);
    u += 0x7FFFu + ((u >> 16) & 1u);   // round-to-nearest-even
    return (u16)(u >> 16);
}

// ---------------- diagnostic: fills fp32 output with a marker ----------------
__global__ __launch_bounds__(256) void marker_k(float* __restrict__ out,
                                                float val, int n) {
    int i = blockIdx.x * 256 + threadIdx.x;
    if (i < n) out[i] = val;
}

// ---------------- P0: We^T -> bf16, and sg[b,d] = g@Wg + bg + be + b2 ----------------
__global__ __launch_bounds__(256) void prep0(
    const float* __restrict__ We, const float* __restrict__ graph,
    const float* __restrict__ Wg, const float* __restrict__ bg,
    const float* __restrict__ be, const float* __restrict__ b2,
    u16* __restrict__ weT, float* __restrict__ sg) {
    int blk = blockIdx.x, tid = threadIdx.x;
    if (blk == 0) {
        for (int idx = tid; idx < 128 * 128; idx += 256) {
            int n = idx >> 7, k = idx & 127;
            weT[idx] = f2bf(We[k * 128 + n]);   // weT[n][k] = We[k][n]
        }
    } else {
        int b = blk - 1;
        if (tid < 128) {
            float acc = bg[tid] + be[tid] + b2[tid];
            for (int k = 0; k < 128; ++k)
                acc += graph[b * 128 + k] * Wg[k * 128 + tid];
            sg[b * 128 + tid] = acc;
        }
    }
}

// ---------------- P1: s1 = zW1+b1, s2c = zW2+sg, values, skip ----------------
__global__ __launch_bounds__(256) void prep1(
    const float* __restrict__ node, const float* __restrict__ hidden,
    const float* __restrict__ Wm, const float* __restrict__ bm,
    const float* __restrict__ Ws, const float* __restrict__ bs,
    const float* __restrict__ W1, const float* __restrict__ b1,
    const float* __restrict__ W2, const float* __restrict__ sg,
    float* __restrict__ s1, float* __restrict__ s2c,
    float* __restrict__ sv, float* __restrict__ ss) {
    __shared__ float zsh[8 * 256];
    int blk = blockIdx.x;            // 256 blocks: 64 per batch, 8 rows each
    int b = blk >> 6;
    int n0 = (blk & 63) << 3;
    int tid = threadIdx.x;
    for (int idx = tid; idx < 8 * 256; idx += 256) {
        int row = idx >> 8, k = idx & 255;
        size_t g = (size_t)(b * NN + n0 + row) * 128;
        zsh[idx] = (k < 128) ? node[g + k] : hidden[g + k - 128];
    }
    __syncthreads();
    int half = tid >> 7;             // 0/1 -> rows 0-3 / 4-7
    int t = tid & 127;               // output dim
    int r0 = half * 4;
    float am[4] = {0,0,0,0}, a1[4] = {0,0,0,0}, a2[4] = {0,0,0,0}, as_[4] = {0,0,0,0};
    for (int k = 0; k < 256; ++k) {
        float wm = Wm[k * 128 + t], w1 = W1[k * 128 + t];
        float w2 = W2[k * 128 + t], ws = Ws[k * 128 + t];
        #pragma unroll
        for (int r = 0; r < 4; ++r) {
            float z = zsh[(r0 + r) * 256 + k];
            am[r] += z * wm; a1[r] += z * w1; a2[r] += z * w2; as_[r] += z * ws;
        }
    }
    float sgv = sg[b * 128 + t];
    #pragma unroll
    for (int r = 0; r < 4; ++r) {
        int n = n0 + r0 + r;
        size_t rowoff = (size_t)(b * NN + n) * 128 + t;
        s1[rowoff]  = a1[r] + b1[t];
        s2c[rowoff] = a2[r] + sgv;
        ss[rowoff]  = as_[r] + bs[t];
        sv[(size_t)((b * HH + (t >> 4)) * NN + n) * 16 + (t & 15)] = am[r] + bm[t];
    }
}

// ---------------- Fused v5b: reg-staged bf16 pipeline + raw barriers (b1 addr FIXED) ----------------
// block = (b,i); 4 waves; wave owns n-cols [wid*32,+32) = heads 2wid,2wid+1.
// Per 32-row strip: wave loads its 8 edge rows to regs (coalesced), converts to
// bf16 (cvt_pk), ds_writes XOR-swizzled; raw s_barrier (NO vmcnt drain) keeps the
// next strip's global loads in flight across the barrier.
__global__ __launch_bounds__(256) void fused_att5(
    const float* __restrict__ edge, const u16* __restrict__ weT,
    const float* __restrict__ s1, const float* __restrict__ s2c,
    const float* __restrict__ adj, const float* __restrict__ Aw,
    const float* __restrict__ Ab, const float* __restrict__ sv,
    const float* __restrict__ ss, float* __restrict__ out) {
    // region0: gemm-phase = bufA(8K)+bufB(8K) bf16 strips; PV-phase = scratch (20480B)
    __shared__ __align__(16) char region0[20480];
    __shared__ float logit_lds[HH][NN];                  // 16 KB
    __shared__ float mask_lds[NN];                       // 2 KB
    char* bufA = region0;
    char* bufB = region0 + 8192;

    const int bid = (blockIdx.x & 7) * 256 + (blockIdx.x >> 3);  // XCD-chunked
    const int i = bid & (NN - 1);
    const int b = bid >> 9;
    const int tid = threadIdx.x;
    const int lane = tid & 63, wid = tid >> 6;
    const int l15 = lane & 15, l4 = lane >> 4;

    const float* ebase = edge + (size_t)(b * NN + i) * NN * 128;
    const float* s1b = s1 + (size_t)b * NN * 128;

    // wave's quarter of a strip: rows [wid*8, +8), 1024 floats, coalesced 1KB/instr
    #define LOADE(e, s) do {                                                \
        const float* sb = ebase + (size_t)(s) * 4096 + wid * 1024;          \
        _Pragma("unroll")                                                   \
        for (int q = 0; q < 4; ++q)                                         \
            e[q] = *(const float4*)(sb + q * 256 + lane * 4);               \
    } while (0)

    // convert 16 floats -> bf16, write 4x8B XOR-swizzled (byte ^= (row&7)<<4)
    #define CVT_WRITE(e, buf) do {                                          \
        _Pragma("unroll")                                                   \
        for (int q = 0; q < 4; ++q) {                                       \
            const int row = (wid << 3) + (q << 1) + (lane >> 5);            \
            const int byt = row * 256 + ((((lane & 31) << 3) ^ ((row & 7) << 4))); \
            union { uint2 u; __bf16 h[4]; } t;                              \
            t.h[0] = (__bf16)e[q].x; t.h[1] = (__bf16)e[q].y;               \
            t.h[2] = (__bf16)e[q].z; t.h[3] = (__bf16)e[q].w;               \
            *(uint2*)(buf + byt) = t.u;                                     \
        }                                                                   \
    } while (0)

    #define LOADS1(sv1, s) do {                                             \
        _Pragma("unroll")                                                   \
        for (int jf = 0; jf < 2; ++jf)                                      \
            _Pragma("unroll")                                               \
            for (int nf = 0; nf < 2; ++nf)                                  \
                sv1[jf][nf] = *(const float4*)(                             \
                    s1b + (size_t)((s) * 32 + jf * 16 + l15) * 128          \
                        + wid * 32 + nf * 16 + l4 * 4);                     \
    } while (0)

    // compute strip s from bf16 buf; epilogue -> logit_lds
    #define COMPUTE(buf, sv1, s) do {                                       \
        f32x4 acc[2][2];                                                    \
        _Pragma("unroll")                                                   \
        for (int nf = 0; nf < 2; ++nf) {                                    \
            const f32x4 ini = {s2v4[nf].x, s2v4[nf].y, s2v4[nf].z, s2v4[nf].w}; \
            acc[nf][0] = ini; acc[nf][1] = ini;                             \
        }                                                                   \
        _Pragma("unroll")                                                   \
        for (int kk = 0; kk < 4; ++kk) {                                    \
            const int ko = (kk * 64 + l4 * 16);                             \
            const bf16x8 b0 = *(const bf16x8*)(buf + (0 * 16 + l15) * 256 + (ko ^ ((l15 & 7) << 4))); \
            const bf16x8 b1 = *(const bf16x8*)(buf + (1 * 16 + l15) * 256 + (ko ^ ((l15 & 7) << 4))); \
            acc[0][0] = __builtin_amdgcn_mfma_f32_16x16x32_bf16(afw[0][kk], b0, acc[0][0], 0, 0, 0); \
            acc[1][0] = __builtin_amdgcn_mfma_f32_16x16x32_bf16(afw[1][kk], b0, acc[1][0], 0, 0, 0); \
            acc[0][1] = __builtin_amdgcn_mfma_f32_16x16x32_bf16(afw[0][kk], b1, acc[0][1], 0, 0, 0); \
            acc[1][1] = __builtin_amdgcn_mfma_f32_16x16x32_bf16(afw[1][kk], b1, acc[1][1], 0, 0, 0); \
        }                                                                   \
        _Pragma("unroll")                                                   \
        for (int jf = 0; jf < 2; ++jf) {                                    \
            _Pragma("unroll")                                               \
            for (int nf = 0; nf < 2; ++nf) {                                \
                const float s1r[4] = {sv1[jf][nf].x, sv1[jf][nf].y,         \
                                      sv1[jf][nf].z, sv1[jf][nf].w};        \
                const float awr[4] = {aw4[nf].x, aw4[nf].y, aw4[nf].z, aw4[nf].w}; \
                float t = 0.0f;                                             \
                _Pragma("unroll")                                           \
                for (int r = 0; r < 4; ++r) {                               \
                    float p = acc[nf][jf][r] + s1r[r];                      \
                    p = fmaxf(p, 0.01f * p);                                \
                    t += p * awr[r];                                        \
                }                                                           \
                t += __shfl_xor(t, 16);                                     \
                t += __shfl_xor(t, 32);                                     \
                if (lane < 16)                                              \
                    logit_lds[wid * 2 + nf][(s) * 32 + jf * 16 + l15] = t + abv[nf]; \
            }                                                               \
        }                                                                   \
    } while (0)

    #define BARRIER_NOVM() do {                                             \
        __builtin_amdgcn_sched_barrier(0);                                  \
        asm volatile("s_waitcnt lgkmcnt(0)" ::: "memory");                  \
        __builtin_amdgcn_s_barrier();                                       \
        __builtin_amdgcn_sched_barrier(0);                                  \
    } while (0)

    float4 eA[4], eB[4];
    LOADE(eA, 0);

    // A-fragments: weT rows n = wid*32+nf*16+l15 (L2-resident)
    bf16x8 afw[2][4];
    #pragma unroll
    for (int nf = 0; nf < 2; ++nf) {
        const int bn = wid * 32 + nf * 16 + l15;
        #pragma unroll
        for (int kk = 0; kk < 4; ++kk)
            afw[nf][kk] = *(const bf16x8*)(weT + bn * 128 + kk * 32 + l4 * 8);
    }

    const float* arow = adj + (size_t)(b * NN + i) * NN;
    for (int j = tid; j < NN; j += 256) mask_lds[j] = (arow[j] - 1.0f) * 1e9f;

    float4 s2v4[2], aw4[2];
    float abv[2];
    #pragma unroll
    for (int nf = 0; nf < 2; ++nf) {
        const int n0 = wid * 32 + nf * 16 + l4 * 4;
        s2v4[nf] = *(const float4*)(s2c + (size_t)(b * NN + i) * 128 + n0);
        aw4[nf]  = *(const float4*)(Aw + n0);
        abv[nf]  = Ab[wid * 2 + nf];
    }
    __syncthreads();   // mask_lds visible (one full barrier; eA may drain, fine)

    float4 s1vA[2][2], s1vB[2][2];
    for (int t2 = 0; t2 < 8; ++t2) {
        const int sA = 2 * t2, sB = 2 * t2 + 1;
        // ---- phase A: strip sA (regs eA -> bufA) ----
        LOADS1(s1vA, sA);
        LOADE(eB, sB);                     // prefetch: stays in flight across barrier
        CVT_WRITE(eA, bufA);               // waits vmcnt for eA only (oldest)
        BARRIER_NOVM();
        COMPUTE(bufA, s1vA, sA);           // s1 wait leaves eB in flight
        // ---- phase B: strip sB (regs eB -> bufB) ----
        LOADS1(s1vB, sB);
        if (sB + 1 < 16) LOADE(eA, sB + 1);
        CVT_WRITE(eB, bufB);
        BARRIER_NOVM();
        COMPUTE(bufB, s1vB, sB);
    }
    __syncthreads();   // logits visible to all

    // masked softmax: wave wid handles heads 2wid, 2wid+1
    #pragma unroll
    for (int hh = 0; hh < 2; ++hh) {
        const int h = wid * 2 + hh;
        float lv[8];
        float m = -3.0e38f;
        #pragma unroll
        for (int q = 0; q < 8; ++q) {
            float l = logit_lds[h][lane + q * 64] + mask_lds[lane + q * 64];
            lv[q] = l;
            m = fmaxf(m, l);
        }
        #pragma unroll
        for (int off = 32; off; off >>= 1) m = fmaxf(m, __shfl_xor(m, off));
        float s = 0.0f;
        #pragma unroll
        for (int q = 0; q < 8; ++q) { lv[q] = __expf(lv[q] - m); s += lv[q]; }
        #pragma unroll
        for (int off = 32; off; off >>= 1) s += __shfl_xor(s, off);
        const float inv = 1.0f / s;
        #pragma unroll
        for (int q = 0; q < 8; ++q)
            logit_lds[h][lane + q * 64] = lv[q] * inv;
    }
    __syncthreads();

    // PV: wave wid -> heads 2wid,2wid+1; lane owns j = q*64+lane; coalesced sv reads
    float* scr = (float*)region0 + wid * 1280;   // 64 lanes x 20 floats
    const float* ssb = ss + (size_t)(b * NN + i) * 128;
    float outv[2];
    #pragma unroll
    for (int hh = 0; hh < 2; ++hh) {
        const int h = wid * 2 + hh;
        const float* svh = sv + (size_t)(b * HH + h) * NN * 16;
        f32x4 a0 = {0,0,0,0}, a1 = {0,0,0,0}, a2 = {0,0,0,0}, a3 = {0,0,0,0};
        #pragma unroll
        for (int q = 0; q < 8; ++q) {
            const int j = q * 64 + lane;
            const float c = logit_lds[h][j];
            const float4* vj = (const float4*)(svh + (size_t)j * 16);
            const float4 v0 = vj[0], v1 = vj[1], v2 = vj[2], v3 = vj[3];
            a0[0] += c * v0.x; a0[1] += c * v0.y; a0[2] += c * v0.z; a0[3] += c * v0.w;
            a1[0] += c * v1.x; a1[1] += c * v1.y; a1[2] += c * v1.z; a1[3] += c * v1.w;
            a2[0] += c * v2.x; a2[1] += c * v2.y; a2[2] += c * v2.z; a2[3] += c * v2.w;
            a3[0] += c * v3.x; a3[1] += c * v3.y; a3[2] += c * v3.z; a3[3] += c * v3.w;
        }
        *(f32x4*)(scr + lane * 20 + 0)  = a0;
        *(f32x4*)(scr + lane * 20 + 4)  = a1;
        *(f32x4*)(scr + lane * 20 + 8)  = a2;
        *(f32x4*)(scr + lane * 20 + 12) = a3;
        float p = 0.0f;
        #pragma unroll
        for (int t = 0; t < 16; ++t)
            p += scr[(l4 * 16 + t) * 20 + l15];
        p += __shfl_xor(p, 16);
        p += __shfl_xor(p, 32);
        outv[hh] = p;     // lanes 0-15 hold sum for d = l15
    }
    if (lane < 16) {
        const size_t o = (size_t)(b * NN + i) * 128 + (wid * 2) * 16 + lane;
        out[o]      = fmaxf(outv[0] + ssb[(wid * 2) * 16 + lane], 0.0f);
        out[o + 16] = fmaxf(outv[1] + ssb[(wid * 2) * 16 + lane + 16], 0.0f);
    }
    #undef LOADE
    #undef CVT_WRITE
    #undef LOADS1
    #undef COMPUTE
    #undef BARRIER_NOVM
}

extern "C" void kernel_launch(void* const* d_in, const int* in_sizes, int n_in,
                              void* d_out, int out_size, void* d_ws, size_t ws_size,
                              hipStream_t stream) {
    const float* node   = (const float*)d_in[0];
    const float* edge   = (const float*)d_in[1];
    const float* graph  = (const float*)d_in[2];
    const float* adj    = (const float*)d_in[3];
    const float* hidden = (const float*)d_in[4];
    const float* Wm = (const float*)d_in[5];
    const float* bm = (const float*)d_in[6];
    const float* Ws = (const float*)d_in[7];
    const float* bs = (const float*)d_in[8];
    const float* W1 = (const float*)d_in[9];
    const float* b1 = (const float*)d_in[10];
    const float* W2 = (const float*)d_in[11];
    const float* b2 = (const float*)d_in[12];
    const float* We = (const float*)d_in[13];
    const float* be = (const float*)d_in[14];
    const float* Wg = (const float*)d_in[15];
    const float* bg = (const float*)d_in[16];
    const float* Aw = (const float*)d_in[17];
    const float* Ab = (const float*)d_in[18];

    float* outp = (float*)d_out;   // reference output dtype is float32
    const size_t WS_NEEDED = 34816 + 4u * 1048576u;   // ~4.03 MiB

    if (ws_size < WS_NEEDED) {
        marker_k<<<(out_size + 255) / 256, 256, 0, stream>>>(
            outp, 2000.0f + (float)(ws_size >> 20), out_size);
        return;
    }

    char* ws = (char*)d_ws;
    u16*   weT = (u16*)ws;                                // 32768 B
    float* sg  = (float*)(ws + 32768);                    // 2048 B
    float* s1  = (float*)(ws + 34816);                    // 1 MiB
    float* s2c = (float*)(ws + 34816 + 1048576);          // 1 MiB
    float* sv  = (float*)(ws + 34816 + 2 * 1048576);      // 1 MiB
    float* ss  = (float*)(ws + 34816 + 3 * 1048576);      // 1 MiB

    prep0<<<1 + BB, 256, 0, stream>>>(We, graph, Wg, bg, be, b2, weT, sg);
    prep1<<<256, 256, 0, stream>>>(node, hidden, Wm, bm, Ws, bs, W1, b1, W2,
                                   sg, s1, s2c, sv, ss);
    fused_att5<<<BB * NN, 256, 0, stream>>>(edge, weT, s1, s2c, adj, Aw, Ab,
                                            sv, ss, outp);
}